// Round 2
// baseline (11943.021 us; speedup 1.0000x reference)
//
#include <hip/hip_runtime.h>
#include <stdint.h>

// GRU fused persistent kernel, MI355X gfx950 — round 10.
// History: r1 13.3ms | r2 4.5ms | r3 3.54ms | r7 3.52ms | r8 3.47ms |
// r9 FAILED (absmax 0.78).
// r9 post-mortem: fast-mode used plain `buffer_inv` (no sc bits). On gfx950
// sc1:sc0 is a 2-bit SCOPE field (00=CU, 01=WG [r6 stale-L1], 10=agent,
// 11=system [r7: sc1==sc0sc1]) -> plain buffer_inv is a CU-scope NOP. Fast
// polls span stale vL1 lines forever, spin budget drained, garbage output.
//
// r10 = r9 architecture with the invalidation fixed + self-verifying:
//  - l1_inv is now `buffer_inv sc1` (agent-scope invalidate, the acquire-
//    fence instruction in the gfx940+ memory model). Invalidate of clean
//    vL1 lines; local-L2 dirty exchange lines are the coherence point and
//    survive (and if they didn't, the smoke test below would catch it).
//  - CENSUS (unchanged): WG reads HW_REG_XCC_ID, claims slice slot via
//    device atomics. group == physical XCD -> exchange is intra-XCD by
//    construction. Census failure -> blockIdx-based assignment + slow mode.
//  - NEW SMOKE TEST (one-time, ~us): after census success, each WG tid0
//    plain-stores a token, drains, then polls its in-group neighbor's
//    token via {buffer_inv sc1; plain load} with a small budget. Join via
//    device atomics; if ANY WG failed to see its neighbor's token, ALL 128
//    WGs demote to the proven r8 sc1/MALL protocol (assignment still from
//    census -> consistent). Converts "inv theory wrong" from FAILED run
//    into neutral run with a counter signature (WRITE_SIZE stays ~147MB).
//  - FAST mode: data+flag stores PLAIN (write-through vL1 -> own-XCD L2,
//    ~300cy ack vs ~900 MALL); consumer polls + slab loads PLAIN, each
//    poll preceded by buffer_inv sc1 so no stale vL1 line can be re-hit.
//    Any vL1 refill between a consumer's inv and its slab read is a fresh
//    L2 fill = current data (producers' vmcnt(0)-drained stores are in L2
//    before their flag is set; flag readers follow program order).
//  - Flag/ordering proof carried from r8/r9: wave w of WG Q sets flag(t)
//    only after (a) the phase barrier joining all 8 waves' slab reads of
//    step t-1 inputs and (b) its own data stores drained (vmcnt0). A
//    consumer's post-barrier actions follow its 8 waves' 16-flag waits
//    whose union = all 16 WGs of the group -> rh overwrite (t+1 vs t
//    readers) and h parity overwrite (t+2 vs t readers) are safe.
//  - All spins budget-bounded: no hang possible; failures are loud.
//
// ws (dwords): hb[2][8][8][512]=65536 | rhb[8][8][512]=32768 | hfl 8x512 |
// rfl 8x512 | census/smoke 160. Total 106656 dw = 427KB, all zeroed.

#define GT    512
#define GDIN  512
#define GDOUT 512
#define NGRP  8
#define NSL   16
#define GROWS 8
#define COLS  32
#define NWAVE 8
#define KW    64
#define NWG   (NGRP * NSL)                          // 128

#define OFF_HB    0
#define OFF_RHB   (2 * NGRP * GROWS * GDOUT)        // 65536
#define OFF_HFL   (OFF_RHB + NGRP * GROWS * GDOUT)  // 98304
#define FLSTR     4                                  // 16B per flag
#define FLGRP     (NSL * NWAVE * FLSTR)              // 512 dw per group
#define OFF_RFL   (OFF_HFL + NGRP * FLGRP)           // 102400
#define OFF_CNS   (OFF_RFL + NGRP * FLGRP)           // 106496
#define CNS_DW    160                                // [0..7]cnt [8]tot [9]bad
                                                     // [10]arr2 [11]fail [16..143]tok
#define INIT_DW   (OFF_CNS + CNS_DW)                 // 106656 dw = 427KB

typedef __attribute__((ext_vector_type(8))) short bf16x8;
typedef __attribute__((ext_vector_type(4))) float f32x4;
typedef __attribute__((ext_vector_type(4))) unsigned int u32x4;

__device__ __forceinline__ short f2bf(float f) {
  union { float f; uint32_t u; } v; v.f = f;
  uint32_t r = (v.u + 0x7FFFu + ((v.u >> 16) & 1u)) >> 16;  // RNE
  return (short)(uint16_t)r;
}
__device__ __forceinline__ float bf2f(short s) {
  union { uint32_t u; float f; } v; v.u = ((uint32_t)(uint16_t)s) << 16;
  return v.f;
}
// pack f32 -> (bf16hi<<16)|bf16lo : fp32-grade when expanded hi+lo
__device__ __forceinline__ uint32_t pack_hl(float v) {
  short hi = f2bf(v);
  short lo = f2bf(v - bf2f(hi));
  return ((uint32_t)(uint16_t)hi << 16) | (uint32_t)(uint16_t)lo;
}

__device__ __forceinline__ void st_sc1(uint32_t* p, uint32_t v) {
  asm volatile("global_store_dword %0, %1, off sc1" :: "v"(p), "v"(v) : "memory");
}
__device__ __forceinline__ void st_pl(uint32_t* p, uint32_t v) {
  asm volatile("global_store_dword %0, %1, off" :: "v"(p), "v"(v) : "memory");
}
__device__ __forceinline__ void vm_drain() {
  asm volatile("s_waitcnt vmcnt(0)" ::: "memory");
}
// Agent-scope vL1 invalidate (gfx940+ acquire fence). r9's plain buffer_inv
// was CU-scope == NOP; sc1 is the fix.
__device__ __forceinline__ void l1_inv() {
  asm volatile("buffer_inv sc1" ::: "memory");
}
// explicit plain (CU-scope) load: fresh-from-L2 after l1_inv
__device__ __forceinline__ uint32_t ld_pl(const uint32_t* p) {
  uint32_t v;
  asm volatile("global_load_dword %0, %1, off\n\ts_waitcnt vmcnt(0)"
               : "=v"(v) : "v"(p) : "memory");
  return v;
}

// 4x dwordx4 (one waitcnt): the wave's 16-dword A slab (2 k-subtiles).
__device__ __forceinline__ void slab4_sc1(const uint32_t* base, u32x4 d[4]) {
  asm volatile(
    "global_load_dwordx4 %0, %4, off sc1\n\t"
    "global_load_dwordx4 %1, %4, off offset:16 sc1\n\t"
    "global_load_dwordx4 %2, %4, off offset:128 sc1\n\t"
    "global_load_dwordx4 %3, %4, off offset:144 sc1\n\t"
    "s_waitcnt vmcnt(0)"
    : "=&v"(d[0]), "=&v"(d[1]), "=&v"(d[2]), "=&v"(d[3])
    : "v"(base) : "memory");
}
__device__ __forceinline__ void slab4_pl(const uint32_t* base, u32x4 d[4]) {
  asm volatile(
    "global_load_dwordx4 %0, %4, off\n\t"
    "global_load_dwordx4 %1, %4, off offset:16\n\t"
    "global_load_dwordx4 %2, %4, off offset:128\n\t"
    "global_load_dwordx4 %3, %4, off offset:144\n\t"
    "s_waitcnt vmcnt(0)"
    : "=&v"(d[0]), "=&v"(d[1]), "=&v"(d[2]), "=&v"(d[3])
    : "v"(base) : "memory");
}

// wave waits for its 2 producer WGs (slices 2wv, 2wv+1) x 8 waves = 16 flags.
// FAST: {buffer_inv sc1; plain load} per iter -> fresh from own-XCD L2.
// SLOW: agent-scope (sc1) load via MALL. Bounded: fail loud, never hang.
__device__ __forceinline__ void wait16(const uint32_t* fbase, uint32_t tgt,
                                       int lane, int wv, int fast, int& budget) {
  if (budget <= 0) return;
  const int idx = lane & 15;                       // lanes 16..63 duplicate
  const uint32_t* p = fbase +
      (size_t)(((2 * wv + (idx >> 3)) * NWAVE + (idx & 7)) * FLSTR);
  if (fast) {
    for (;;) {
      l1_inv();
      uint32_t v = ld_pl(p);
      if (__all((int)(v >= tgt))) break;
      if (--budget <= 0) break;
    }
  } else {
    for (;;) {
      uint32_t v = __hip_atomic_load(p, __ATOMIC_RELAXED, __HIP_MEMORY_SCOPE_AGENT);
      if (__all((int)(v >= tgt))) break;
      if (--budget <= 0) break;
    }
  }
  asm volatile("" ::: "memory");
}

// 8 packed words -> hi/lo bf16x8 MFMA A-fragments (pure bit ops)
union U16x8 { uint32_t u[4]; bf16x8 v; };
__device__ __forceinline__ void mk_frags(const u32x4 A, const u32x4 B,
                                         bf16x8& hi, bf16x8& lo) {
  U16x8 h, l;
  h.u[0] = (A[0] >> 16) | (A[1] & 0xFFFF0000u);  l.u[0] = (A[0] & 0xFFFFu) | (A[1] << 16);
  h.u[1] = (A[2] >> 16) | (A[3] & 0xFFFF0000u);  l.u[1] = (A[2] & 0xFFFFu) | (A[3] << 16);
  h.u[2] = (B[0] >> 16) | (B[1] & 0xFFFF0000u);  l.u[2] = (B[0] & 0xFFFFu) | (B[1] << 16);
  h.u[3] = (B[2] >> 16) | (B[3] & 0xFFFF0000u);  l.u[3] = (B[2] & 0xFFFFu) | (B[3] << 16);
  hi = h.v; lo = l.v;
}

__global__ __launch_bounds__(512, 2)
void gru_fused(const float* __restrict__ X, const int* __restrict__ mask,
               const float* __restrict__ Wz, const float* __restrict__ Uz,
               const float* __restrict__ bz,
               const float* __restrict__ Wr, const float* __restrict__ Ur,
               const float* __restrict__ br,
               const float* __restrict__ Wh, const float* __restrict__ Uh,
               const float* __restrict__ bh,
               float* __restrict__ out, uint32_t* __restrict__ ws)
{
  const int tid   = threadIdx.x;
  const int wv    = tid >> 6;          // 0..7
  const int lane  = tid & 63;
  const int col16 = lane & 15;         // MFMA A row / B+D column-in-tile
  const int quad  = lane >> 4;
  const int row8  = lane & 7;          // real batch row (rows 8-15 dup)

  // ---- census (assignment) + smoke test (protocol selection) ----
  uint32_t* cns = ws + OFF_CNS;
  __shared__ int s_mode, s_g, s_sl;
  if (tid == 0) {
    uint32_t xcc = 0;
    asm volatile("s_getreg_b32 %0, hwreg(HW_REG_XCC_ID)" : "=s"(xcc));
    xcc &= 7u;
    uint32_t slot = __hip_atomic_fetch_add(&cns[xcc], 1u, __ATOMIC_RELAXED,
                                           __HIP_MEMORY_SCOPE_AGENT);
    if (slot >= (uint32_t)NSL)
      __hip_atomic_fetch_add(&cns[9], 1u, __ATOMIC_RELAXED, __HIP_MEMORY_SCOPE_AGENT);
    __hip_atomic_fetch_add(&cns[8], 1u, __ATOMIC_RELEASE, __HIP_MEMORY_SCOPE_AGENT);
    uint32_t tv = 0; long sp = 0;
    do {
      tv = __hip_atomic_load(&cns[8], __ATOMIC_ACQUIRE, __HIP_MEMORY_SCOPE_AGENT);
    } while (tv < (uint32_t)NWG && ++sp < 2000000L);
    uint32_t bad = __hip_atomic_load(&cns[9], __ATOMIC_RELAXED, __HIP_MEMORY_SCOPE_AGENT);
    const int cok = (tv >= (uint32_t)NWG && bad == 0u);
    int g_, sl_, mode_ = 0;
    if (cok) {
      g_ = (int)xcc; sl_ = (int)slot;
      // smoke: token through the exact fast path (plain store -> drain ->
      // neighbor polls with inv sc1 + plain load). Any failure demotes ALL.
      uint32_t* tok = cns + 16;
      st_pl(&tok[g_ * NSL + sl_], 1u);
      vm_drain();
      const uint32_t* np = &tok[g_ * NSL + ((sl_ + 1) & (NSL - 1))];
      int ok = 0;
      for (long i = 0; i < 300000L; ++i) {
        l1_inv();
        if (ld_pl(np) != 0u) { ok = 1; break; }
      }
      if (!ok)
        __hip_atomic_fetch_add(&cns[11], 1u, __ATOMIC_RELAXED, __HIP_MEMORY_SCOPE_AGENT);
      __hip_atomic_fetch_add(&cns[10], 1u, __ATOMIC_RELEASE, __HIP_MEMORY_SCOPE_AGENT);
      uint32_t tv2 = 0; sp = 0;
      do {
        tv2 = __hip_atomic_load(&cns[10], __ATOMIC_ACQUIRE, __HIP_MEMORY_SCOPE_AGENT);
      } while (tv2 < (uint32_t)NWG && ++sp < 2000000L);
      uint32_t fl = __hip_atomic_load(&cns[11], __ATOMIC_RELAXED, __HIP_MEMORY_SCOPE_AGENT);
      mode_ = (tv2 >= (uint32_t)NWG && fl == 0u) ? 1 : 0;
    } else {
      g_ = (int)(blockIdx.x & 7); sl_ = (int)(blockIdx.x >> 3);
    }
    s_mode = mode_; s_g = g_; s_sl = sl_;
  }
  __syncthreads();
  const int fast = __builtin_amdgcn_readfirstlane(s_mode);
  const int g    = __builtin_amdgcn_readfirstlane(s_g);
  const int sl   = __builtin_amdgcn_readfirstlane(s_sl);
  l1_inv();                            // vs cross-launch stale vL1

  const int jb = sl * COLS;            // my 32 output columns
  const int kb = wv * KW;              // my 64-wide K range

  uint32_t* hb  = ws + OFF_HB;         // [2][NGRP][GROWS][512] packed hl
  uint32_t* rhb = ws + OFF_RHB;        // [NGRP][GROWS][512] packed hl
  uint32_t* hfl = ws + OFF_HFL + (size_t)g * FLGRP;
  uint32_t* rfl = ws + OFF_RFL + (size_t)g * FLGRP;
  uint32_t* hfl_my = hfl + (size_t)(sl * NWAVE + wv) * FLSTR;
  uint32_t* rfl_my = rfl + (size_t)(sl * NWAVE + wv) * FLSTR;
  uint32_t* rhg = rhb + (size_t)g * (GROWS * GDOUT);
  const int slab_off = row8 * GDOUT + kb + quad * 8;

  // parity LDS scratch, 1 barrier per phase (>=3 barriers between same-
  // parity reuse at t and t+2 -> ordered; r8 argument carried over).
  __shared__ __align__(16) float scrA[2][NWAVE][2][GROWS][COLS];  // 32KB
  __shared__ __align__(16) float scrB[2][NWAVE][GROWS][COLS];     // 16KB

  // ---------- one-time: weight B-fragments into registers ----------
  // per wave: 2 k-subtiles x 2 col-tiles x 9 matrices = 36 frags = 144 VGPR
  bf16x8 uzh[2][2], uzl[2][2], urh[2][2], url[2][2], uhh[2][2], uhl[2][2];
  bf16x8 wzf[2][2], wrf[2][2], whf[2][2];
#pragma unroll
  for (int c = 0; c < 2; ++c) {
#pragma unroll
    for (int Tt = 0; Tt < 2; ++Tt) {
      const int k0 = kb + c * 32 + quad * 8;
      const int j  = jb + Tt * 16 + col16;
      bf16x8 t_uzh, t_uzl, t_urh, t_url, t_uhh, t_uhl, t_wz, t_wr, t_wh;
#pragma unroll
      for (int i = 0; i < 8; ++i) {
        const int idx = (k0 + i) * GDOUT + j;
        float u; short hi;
        u = Uz[idx]; hi = f2bf(u); t_uzh[i] = hi; t_uzl[i] = f2bf(u - bf2f(hi));
        u = Ur[idx]; hi = f2bf(u); t_urh[i] = hi; t_url[i] = f2bf(u - bf2f(hi));
        u = Uh[idx]; hi = f2bf(u); t_uhh[i] = hi; t_uhl[i] = f2bf(u - bf2f(hi));
        t_wz[i] = f2bf(Wz[idx]);
        t_wr[i] = f2bf(Wr[idx]);
        t_wh[i] = f2bf(Wh[idx]);
      }
      uzh[c][Tt] = t_uzh; uzl[c][Tt] = t_uzl; urh[c][Tt] = t_urh; url[c][Tt] = t_url;
      uhh[c][Tt] = t_uhh; uhl[c][Tt] = t_uhl;
      wzf[c][Tt] = t_wz;  wrf[c][Tt] = t_wr;  whf[c][Tt] = t_wh;
    }
  }

  const int ecol = lane & 31;                    // epilogue column (lanes<32 real)
  const float bzv = bz[jb + ecol];
  const float brv = br[jb + ecol];
  const float bhv = bh[jb + ecol];
  const int b_ep = GROWS * g + wv;               // epilogue batch row (wave==row)

  float hreg = 0.f;      // h(t) at (b_ep, jb+ecol), exact f32 (producer-side)
  float zvl  = 0.f;      // carried phase A -> phase B
  int budget = 4000000;  // bounded spins: fail loud, never hang

  for (int t = 0; t < GT; ++t) {
    const int par = t & 1;
    // ---- pre-wait: X fragments + mask (off the sync critical path) ----
    bf16x8 xa[2];
#pragma unroll
    for (int c = 0; c < 2; ++c) {
      const int k0 = kb + c * 32 + quad * 8;
      const float* xp = X + ((size_t)(GROWS * g + row8) * GT + t) * GDIN + k0;
      f32x4 x0 = *(const f32x4*)xp;
      f32x4 x1 = *(const f32x4*)(xp + 4);
      bf16x8 xf;
#pragma unroll
      for (int i = 0; i < 4; ++i) { xf[i] = f2bf(x0[i]); xf[i + 4] = f2bf(x1[i]); }
      xa[c] = xf;
    }
    const int mk = mask[(size_t)b_ep * GT + t];

    // ---- phase A: wait h(t), slab, frags, MFMAs (z, r, x-proj) ----
    if (t) wait16(hfl, (uint32_t)t, lane, wv, fast, budget);
    const uint32_t* hsrc = hb + ((size_t)par * NGRP + g) * (GROWS * GDOUT) + slab_off;
    u32x4 hd[4];
    if (fast) slab4_pl(hsrc, hd); else slab4_sc1(hsrc, hd);

    f32x4 az[2]  = {{0,0,0,0},{0,0,0,0}}, az2[2] = {{0,0,0,0},{0,0,0,0}};
    f32x4 ar[2]  = {{0,0,0,0},{0,0,0,0}}, ar2[2] = {{0,0,0,0},{0,0,0,0}};
    f32x4 ah[2]  = {{0,0,0,0},{0,0,0,0}};
#pragma unroll
    for (int c = 0; c < 2; ++c) {
      bf16x8 hhi, hlo;
      mk_frags(hd[2 * c], hd[2 * c + 1], hhi, hlo);
#pragma unroll
      for (int Tt = 0; Tt < 2; ++Tt) {   // independent chains for MFMA ILP
        az[Tt]  = __builtin_amdgcn_mfma_f32_16x16x32_bf16(hhi, uzh[c][Tt], az[Tt],  0, 0, 0);
        az2[Tt] = __builtin_amdgcn_mfma_f32_16x16x32_bf16(hlo, uzh[c][Tt], az2[Tt], 0, 0, 0);
        az[Tt]  = __builtin_amdgcn_mfma_f32_16x16x32_bf16(hhi, uzl[c][Tt], az[Tt],  0, 0, 0);
        az2[Tt] = __builtin_amdgcn_mfma_f32_16x16x32_bf16(xa[c], wzf[c][Tt], az2[Tt], 0, 0, 0);
        ar[Tt]  = __builtin_amdgcn_mfma_f32_16x16x32_bf16(hhi, urh[c][Tt], ar[Tt],  0, 0, 0);
        ar2[Tt] = __builtin_amdgcn_mfma_f32_16x16x32_bf16(hlo, urh[c][Tt], ar2[Tt], 0, 0, 0);
        ar[Tt]  = __builtin_amdgcn_mfma_f32_16x16x32_bf16(hhi, url[c][Tt], ar[Tt],  0, 0, 0);
        ar2[Tt] = __builtin_amdgcn_mfma_f32_16x16x32_bf16(xa[c], wrf[c][Tt], ar2[Tt], 0, 0, 0);
        ah[Tt]  = __builtin_amdgcn_mfma_f32_16x16x32_bf16(xa[c], whf[c][Tt], ah[Tt],  0, 0, 0);
      }
    }

    // ---- distributed reduce + per-wave rh release (1 barrier) ----
    if (quad < 2) {                      // quads 0-1 hold real rows 0-7
#pragma unroll
      for (int Tt = 0; Tt < 2; ++Tt)
#pragma unroll
        for (int rr = 0; rr < 4; ++rr) {
          scrA[par][wv][0][quad * 4 + rr][Tt * 16 + col16] = az[Tt][rr] + az2[Tt][rr];
          scrA[par][wv][1][quad * 4 + rr][Tt * 16 + col16] = ar[Tt][rr] + ar2[Tt][rr];
        }
    }
    __syncthreads();                     // joins all 8 waves' h-waits (all-16 coverage)

    float zsum = 0.f, rsum = 0.f;
#pragma unroll
    for (int w2 = 0; w2 < NWAVE; ++w2) {
      zsum += scrA[par][w2][0][wv][ecol];
      rsum += scrA[par][w2][1][wv][ecol];
    }
    zvl = 1.f / (1.f + __expf(-(zsum + bzv)));
    const float rvl = 1.f / (1.f + __expf(-(rsum + brv)));
    if (lane < 32) {
      uint32_t* dst = rhg + (size_t)wv * GDOUT + jb + lane;
      const uint32_t pv = pack_hl(rvl * hreg);
      if (fast) st_pl(dst, pv); else st_sc1(dst, pv);
    }
    vm_drain();                          // my 32 rh dwords committed (L2/MALL)
    if (lane == 0) {
      if (fast) st_pl(rfl_my, (uint32_t)(t + 1)); else st_sc1(rfl_my, (uint32_t)(t + 1));
    }

    // ---- phase B: wait rh(t), slab, 3 MFMA chains (Uh) ----
    wait16(rfl, (uint32_t)(t + 1), lane, wv, fast, budget);
    u32x4 rd[4];
    const uint32_t* rsrc = rhg + slab_off;
    if (fast) slab4_pl(rsrc, rd); else slab4_sc1(rsrc, rd);

    f32x4 b1[2] = {{0,0,0,0},{0,0,0,0}}, b2[2] = {{0,0,0,0},{0,0,0,0}};
    f32x4 b3[2] = {{0,0,0,0},{0,0,0,0}};
#pragma unroll
    for (int c = 0; c < 2; ++c) {
      bf16x8 th, tl;
      mk_frags(rd[2 * c], rd[2 * c + 1], th, tl);
#pragma unroll
      for (int Tt = 0; Tt < 2; ++Tt) {
        b1[Tt] = __builtin_amdgcn_mfma_f32_16x16x32_bf16(th, uhh[c][Tt], b1[Tt], 0, 0, 0);
        b2[Tt] = __builtin_amdgcn_mfma_f32_16x16x32_bf16(tl, uhh[c][Tt], b2[Tt], 0, 0, 0);
        b3[Tt] = __builtin_amdgcn_mfma_f32_16x16x32_bf16(th, uhl[c][Tt], b3[Tt], 0, 0, 0);
      }
    }

    if (quad < 2) {
#pragma unroll
      for (int Tt = 0; Tt < 2; ++Tt)
#pragma unroll
        for (int rr = 0; rr < 4; ++rr)
          scrB[par][wv][quad * 4 + rr][Tt * 16 + col16] =
              ah[Tt][rr] + b1[Tt][rr] + b2[Tt][rr] + b3[Tt][rr];
    }
    __syncthreads();                     // joins all 8 waves' rh-waits (all-16 coverage)

    float hsum = 0.f;
#pragma unroll
    for (int w2 = 0; w2 < NWAVE; ++w2) hsum += scrB[par][w2][wv][ecol];
    const float pre = hsum + bhv;
    const float e  = __expf(2.f * pre);              // tanh, saturation-safe
    const float hh = 1.f - 2.f / (e + 1.f);
    float hn = zvl * hreg + (1.f - zvl) * hh;
    hn = (mk > 0) ? hn : hreg;
    hreg = hn;

    if (lane < 32) {
      uint32_t* hdst = hb + ((size_t)((t + 1) & 1) * NGRP + g) * (GROWS * GDOUT)
                         + (size_t)wv * GDOUT + jb + lane;
      const uint32_t pv = pack_hl(hn);
      if (fast) st_pl(hdst, pv); else st_sc1(hdst, pv);
      if (t == GT - 1) out[(size_t)b_ep * GDOUT + jb + lane] = hn;
    }
    vm_drain();                          // my 32 h dwords committed
    if (lane == 0) {
      if (fast) st_pl(hfl_my, (uint32_t)(t + 1)); else st_sc1(hfl_my, (uint32_t)(t + 1));
    }
  }
}

extern "C" void kernel_launch(void* const* d_in, const int* in_sizes, int n_in,
                              void* d_out, int out_size, void* d_ws, size_t ws_size,
                              hipStream_t stream) {
  const float* X  = (const float*)d_in[0];
  const int* mask = (const int*)d_in[1];
  const float* Wz = (const float*)d_in[2];
  const float* Uz = (const float*)d_in[3];
  const float* bz = (const float*)d_in[4];
  const float* Wr = (const float*)d_in[5];
  const float* Ur = (const float*)d_in[6];
  const float* br = (const float*)d_in[7];
  const float* Wh = (const float*)d_in[8];
  const float* Uh = (const float*)d_in[9];
  const float* bh = (const float*)d_in[10];

  // zero h slot0 (packed 0x0 == 0.0f), rhb, flags, census/smoke
  hipMemsetAsync(d_ws, 0, (size_t)INIT_DW * 4, stream);

  hipLaunchKernelGGL(gru_fused, dim3(NWG), dim3(512), 0, stream,
                     X, mask, Wz, Uz, bz, Wr, Ur, br, Wh, Uh, bh,
                     (float*)d_out, (uint32_t*)d_ws);
}

// Round 3
// 2642.813 us; speedup vs baseline: 4.5191x; 4.5191x over previous
//
#include <hip/hip_runtime.h>
#include <stdint.h>

// GRU fused persistent kernel, MI355X gfx950 — round 11.
// History: r1 13.3ms | r2 4.5ms | r3 3.54ms | r7 3.52ms | r8 3.47ms (MALL
// sc1 protocol) | r9 FAILED (plain buffer_inv = CU-scope NOP) | r10 PASSED
// but 11.9ms: XCD-local fast mode ENGAGED and CORRECT (WRITE_SIZE 147MB ->
// 2.3MB proves it), but per-poll `buffer_inv sc1` is catastrophic: 128
// waves/XCD hammering agent-scope vL1 invalidates serializes CU memory
// pipes -> 11.66us/round vs MALL's 3.39us/round.
//
// r11 = r10 architecture, acquire primitive replaced by NT loads:
//  - Consumer polls + slab loads use the `nt` (non-temporal, NO-ALLOCATE)
//    cache policy: probe vL1 (permanent miss: exchange lines are only ever
//    touched by nt loads and write-through stores, so they never enter
//    vL1), serviced by the LOCAL XCD L2 = the very cache the producer's
//    vmcnt-drained plain stores committed to. No invalidate instructions
//    at all; poll period ~ one L2 hit.
//  - Self-verifying: the one-time smoke test now exercises the exact nt
//    path (plain store -> drain -> neighbor nt-polls). If nt hits stale
//    vL1 (no-allocate not honored) or bypasses L2 to stale MALL, the
//    smoke times out and ALL 128 WGs demote to the r8 sc1/MALL protocol
//    (proven 3.47ms) -> neutral run, counter signature WRITE_SIZE ~147MB.
//  - Producer side UNCHANGED from r10 (hardware-proven over 1024 rounds):
//    plain data stores (write-through vL1 -> own-XCD L2), vmcnt(0) drain,
//    then plain flag store. Consumer sees flag in L2 only after data.
//  - CENSUS (unchanged): WG reads HW_REG_XCC_ID, claims slice slot via
//    device atomics -> group == physical XCD, exchange intra-XCD by
//    construction. Census failure -> blockIdx assignment + slow mode.
//  - Flag/ordering proof carried from r8/r9/r10: wave w of WG Q sets
//    flag(t) only after (a) the phase barrier joining all 8 waves' slab
//    reads of step t-1 inputs and (b) its own data stores drained. A
//    consumer's post-barrier actions follow its 8 waves' 16-flag waits
//    whose union = all 16 WGs of the group -> rh overwrite (t+1 vs t
//    readers) and h parity overwrite (t+2 vs t readers) are safe.
//  - All spins budget-bounded: no hang possible; failures are loud.
//
// ws (dwords): hb[2][8][8][512]=65536 | rhb[8][8][512]=32768 | hfl 8x512 |
// rfl 8x512 | census/smoke 160. Total 106656 dw = 427KB, all zeroed.

#define GT    512
#define GDIN  512
#define GDOUT 512
#define NGRP  8
#define NSL   16
#define GROWS 8
#define COLS  32
#define NWAVE 8
#define KW    64
#define NWG   (NGRP * NSL)                          // 128

#define OFF_HB    0
#define OFF_RHB   (2 * NGRP * GROWS * GDOUT)        // 65536
#define OFF_HFL   (OFF_RHB + NGRP * GROWS * GDOUT)  // 98304
#define FLSTR     4                                  // 16B per flag
#define FLGRP     (NSL * NWAVE * FLSTR)              // 512 dw per group
#define OFF_RFL   (OFF_HFL + NGRP * FLGRP)           // 102400
#define OFF_CNS   (OFF_RFL + NGRP * FLGRP)           // 106496
#define CNS_DW    160                                // [0..7]cnt [8]tot [9]bad
                                                     // [10]arr2 [11]fail [16..143]tok
#define INIT_DW   (OFF_CNS + CNS_DW)                 // 106656 dw = 427KB

typedef __attribute__((ext_vector_type(8))) short bf16x8;
typedef __attribute__((ext_vector_type(4))) float f32x4;
typedef __attribute__((ext_vector_type(4))) unsigned int u32x4;

__device__ __forceinline__ short f2bf(float f) {
  union { float f; uint32_t u; } v; v.f = f;
  uint32_t r = (v.u + 0x7FFFu + ((v.u >> 16) & 1u)) >> 16;  // RNE
  return (short)(uint16_t)r;
}
__device__ __forceinline__ float bf2f(short s) {
  union { uint32_t u; float f; } v; v.u = ((uint32_t)(uint16_t)s) << 16;
  return v.f;
}
// pack f32 -> (bf16hi<<16)|bf16lo : fp32-grade when expanded hi+lo
__device__ __forceinline__ uint32_t pack_hl(float v) {
  short hi = f2bf(v);
  short lo = f2bf(v - bf2f(hi));
  return ((uint32_t)(uint16_t)hi << 16) | (uint32_t)(uint16_t)lo;
}

__device__ __forceinline__ void st_sc1(uint32_t* p, uint32_t v) {
  asm volatile("global_store_dword %0, %1, off sc1" :: "v"(p), "v"(v) : "memory");
}
__device__ __forceinline__ void st_pl(uint32_t* p, uint32_t v) {
  asm volatile("global_store_dword %0, %1, off" :: "v"(p), "v"(v) : "memory");
}
__device__ __forceinline__ void vm_drain() {
  asm volatile("s_waitcnt vmcnt(0)" ::: "memory");
}
// one-time agent-scope vL1 invalidate (startup hygiene only — NOT on the
// per-round path; r10 proved per-poll inv costs 3.4x).
__device__ __forceinline__ void l1_inv() {
  asm volatile("buffer_inv sc1" ::: "memory");
}
// NT load: no-allocate in vL1 -> always serviced fresh from local-XCD L2.
__device__ __forceinline__ uint32_t ld_nt(const uint32_t* p) {
  uint32_t v;
  asm volatile("global_load_dword %0, %1, off nt\n\ts_waitcnt vmcnt(0)"
               : "=v"(v) : "v"(p) : "memory");
  return v;
}

// 4x dwordx4 (one waitcnt): the wave's 16-dword A slab (2 k-subtiles).
__device__ __forceinline__ void slab4_sc1(const uint32_t* base, u32x4 d[4]) {
  asm volatile(
    "global_load_dwordx4 %0, %4, off sc1\n\t"
    "global_load_dwordx4 %1, %4, off offset:16 sc1\n\t"
    "global_load_dwordx4 %2, %4, off offset:128 sc1\n\t"
    "global_load_dwordx4 %3, %4, off offset:144 sc1\n\t"
    "s_waitcnt vmcnt(0)"
    : "=&v"(d[0]), "=&v"(d[1]), "=&v"(d[2]), "=&v"(d[3])
    : "v"(base) : "memory");
}
__device__ __forceinline__ void slab4_nt(const uint32_t* base, u32x4 d[4]) {
  asm volatile(
    "global_load_dwordx4 %0, %4, off nt\n\t"
    "global_load_dwordx4 %1, %4, off offset:16 nt\n\t"
    "global_load_dwordx4 %2, %4, off offset:128 nt\n\t"
    "global_load_dwordx4 %3, %4, off offset:144 nt\n\t"
    "s_waitcnt vmcnt(0)"
    : "=&v"(d[0]), "=&v"(d[1]), "=&v"(d[2]), "=&v"(d[3])
    : "v"(base) : "memory");
}

// wave waits for its 2 producer WGs (slices 2wv, 2wv+1) x 8 waves = 16 flags.
// FAST: nt poll (fresh from own-XCD L2, ~L2-hit period, no invalidates).
// SLOW: agent-scope (sc1) load via MALL. Bounded: fail loud, never hang.
__device__ __forceinline__ void wait16(const uint32_t* fbase, uint32_t tgt,
                                       int lane, int wv, int fast, int& budget) {
  if (budget <= 0) return;
  const int idx = lane & 15;                       // lanes 16..63 duplicate
  const uint32_t* p = fbase +
      (size_t)(((2 * wv + (idx >> 3)) * NWAVE + (idx & 7)) * FLSTR);
  if (fast) {
    for (;;) {
      uint32_t v = ld_nt(p);
      if (__all((int)(v >= tgt))) break;
      if (--budget <= 0) break;
    }
  } else {
    for (;;) {
      uint32_t v = __hip_atomic_load(p, __ATOMIC_RELAXED, __HIP_MEMORY_SCOPE_AGENT);
      if (__all((int)(v >= tgt))) break;
      if (--budget <= 0) break;
    }
  }
  asm volatile("" ::: "memory");
}

// 8 packed words -> hi/lo bf16x8 MFMA A-fragments (pure bit ops)
union U16x8 { uint32_t u[4]; bf16x8 v; };
__device__ __forceinline__ void mk_frags(const u32x4 A, const u32x4 B,
                                         bf16x8& hi, bf16x8& lo) {
  U16x8 h, l;
  h.u[0] = (A[0] >> 16) | (A[1] & 0xFFFF0000u);  l.u[0] = (A[0] & 0xFFFFu) | (A[1] << 16);
  h.u[1] = (A[2] >> 16) | (A[3] & 0xFFFF0000u);  l.u[1] = (A[2] & 0xFFFFu) | (A[3] << 16);
  h.u[2] = (B[0] >> 16) | (B[1] & 0xFFFF0000u);  l.u[2] = (B[0] & 0xFFFFu) | (B[1] << 16);
  h.u[3] = (B[2] >> 16) | (B[3] & 0xFFFF0000u);  l.u[3] = (B[2] & 0xFFFFu) | (B[3] << 16);
  hi = h.v; lo = l.v;
}

__global__ __launch_bounds__(512, 2)
void gru_fused(const float* __restrict__ X, const int* __restrict__ mask,
               const float* __restrict__ Wz, const float* __restrict__ Uz,
               const float* __restrict__ bz,
               const float* __restrict__ Wr, const float* __restrict__ Ur,
               const float* __restrict__ br,
               const float* __restrict__ Wh, const float* __restrict__ Uh,
               const float* __restrict__ bh,
               float* __restrict__ out, uint32_t* __restrict__ ws)
{
  const int tid   = threadIdx.x;
  const int wv    = tid >> 6;          // 0..7
  const int lane  = tid & 63;
  const int col16 = lane & 15;         // MFMA A row / B+D column-in-tile
  const int quad  = lane >> 4;
  const int row8  = lane & 7;          // real batch row (rows 8-15 dup)

  // ---- census (assignment) + smoke test (protocol selection) ----
  uint32_t* cns = ws + OFF_CNS;
  __shared__ int s_mode, s_g, s_sl;
  if (tid == 0) {
    uint32_t xcc = 0;
    asm volatile("s_getreg_b32 %0, hwreg(HW_REG_XCC_ID)" : "=s"(xcc));
    xcc &= 7u;
    uint32_t slot = __hip_atomic_fetch_add(&cns[xcc], 1u, __ATOMIC_RELAXED,
                                           __HIP_MEMORY_SCOPE_AGENT);
    if (slot >= (uint32_t)NSL)
      __hip_atomic_fetch_add(&cns[9], 1u, __ATOMIC_RELAXED, __HIP_MEMORY_SCOPE_AGENT);
    __hip_atomic_fetch_add(&cns[8], 1u, __ATOMIC_RELEASE, __HIP_MEMORY_SCOPE_AGENT);
    uint32_t tv = 0; long sp = 0;
    do {
      tv = __hip_atomic_load(&cns[8], __ATOMIC_ACQUIRE, __HIP_MEMORY_SCOPE_AGENT);
    } while (tv < (uint32_t)NWG && ++sp < 2000000L);
    uint32_t bad = __hip_atomic_load(&cns[9], __ATOMIC_RELAXED, __HIP_MEMORY_SCOPE_AGENT);
    const int cok = (tv >= (uint32_t)NWG && bad == 0u);
    int g_, sl_, mode_ = 0;
    if (cok) {
      g_ = (int)xcc; sl_ = (int)slot;
      // smoke: token through the exact fast path (plain store -> drain ->
      // neighbor nt-polls). Any failure (stale vL1 hit / L2 bypass to
      // stale MALL) demotes ALL 128 WGs to the proven sc1 protocol.
      l1_inv();                       // hygiene before the nt experiment
      uint32_t* tok = cns + 16;
      st_pl(&tok[g_ * NSL + sl_], 1u);
      vm_drain();
      const uint32_t* np = &tok[g_ * NSL + ((sl_ + 1) & (NSL - 1))];
      int ok = 0;
      for (long i = 0; i < 300000L; ++i) {
        if (ld_nt(np) != 0u) { ok = 1; break; }
      }
      if (!ok)
        __hip_atomic_fetch_add(&cns[11], 1u, __ATOMIC_RELAXED, __HIP_MEMORY_SCOPE_AGENT);
      __hip_atomic_fetch_add(&cns[10], 1u, __ATOMIC_RELEASE, __HIP_MEMORY_SCOPE_AGENT);
      uint32_t tv2 = 0; sp = 0;
      do {
        tv2 = __hip_atomic_load(&cns[10], __ATOMIC_ACQUIRE, __HIP_MEMORY_SCOPE_AGENT);
      } while (tv2 < (uint32_t)NWG && ++sp < 2000000L);
      uint32_t fl = __hip_atomic_load(&cns[11], __ATOMIC_RELAXED, __HIP_MEMORY_SCOPE_AGENT);
      mode_ = (tv2 >= (uint32_t)NWG && fl == 0u) ? 1 : 0;
    } else {
      g_ = (int)(blockIdx.x & 7); sl_ = (int)(blockIdx.x >> 3);
    }
    s_mode = mode_; s_g = g_; s_sl = sl_;
  }
  __syncthreads();
  const int fast = __builtin_amdgcn_readfirstlane(s_mode);
  const int g    = __builtin_amdgcn_readfirstlane(s_g);
  const int sl   = __builtin_amdgcn_readfirstlane(s_sl);
  l1_inv();                            // one-time: clear cross-launch vL1

  const int jb = sl * COLS;            // my 32 output columns
  const int kb = wv * KW;              // my 64-wide K range

  uint32_t* hb  = ws + OFF_HB;         // [2][NGRP][GROWS][512] packed hl
  uint32_t* rhb = ws + OFF_RHB;        // [NGRP][GROWS][512] packed hl
  uint32_t* hfl = ws + OFF_HFL + (size_t)g * FLGRP;
  uint32_t* rfl = ws + OFF_RFL + (size_t)g * FLGRP;
  uint32_t* hfl_my = hfl + (size_t)(sl * NWAVE + wv) * FLSTR;
  uint32_t* rfl_my = rfl + (size_t)(sl * NWAVE + wv) * FLSTR;
  uint32_t* rhg = rhb + (size_t)g * (GROWS * GDOUT);
  const int slab_off = row8 * GDOUT + kb + quad * 8;

  // parity LDS scratch, 1 barrier per phase (>=3 barriers between same-
  // parity reuse at t and t+2 -> ordered; r8 argument carried over).
  __shared__ __align__(16) float scrA[2][NWAVE][2][GROWS][COLS];  // 32KB
  __shared__ __align__(16) float scrB[2][NWAVE][GROWS][COLS];     // 16KB

  // ---------- one-time: weight B-fragments into registers ----------
  // per wave: 2 k-subtiles x 2 col-tiles x 9 matrices = 36 frags = 144 VGPR
  bf16x8 uzh[2][2], uzl[2][2], urh[2][2], url[2][2], uhh[2][2], uhl[2][2];
  bf16x8 wzf[2][2], wrf[2][2], whf[2][2];
#pragma unroll
  for (int c = 0; c < 2; ++c) {
#pragma unroll
    for (int Tt = 0; Tt < 2; ++Tt) {
      const int k0 = kb + c * 32 + quad * 8;
      const int j  = jb + Tt * 16 + col16;
      bf16x8 t_uzh, t_uzl, t_urh, t_url, t_uhh, t_uhl, t_wz, t_wr, t_wh;
#pragma unroll
      for (int i = 0; i < 8; ++i) {
        const int idx = (k0 + i) * GDOUT + j;
        float u; short hi;
        u = Uz[idx]; hi = f2bf(u); t_uzh[i] = hi; t_uzl[i] = f2bf(u - bf2f(hi));
        u = Ur[idx]; hi = f2bf(u); t_urh[i] = hi; t_url[i] = f2bf(u - bf2f(hi));
        u = Uh[idx]; hi = f2bf(u); t_uhh[i] = hi; t_uhl[i] = f2bf(u - bf2f(hi));
        t_wz[i] = f2bf(Wz[idx]);
        t_wr[i] = f2bf(Wr[idx]);
        t_wh[i] = f2bf(Wh[idx]);
      }
      uzh[c][Tt] = t_uzh; uzl[c][Tt] = t_uzl; urh[c][Tt] = t_urh; url[c][Tt] = t_url;
      uhh[c][Tt] = t_uhh; uhl[c][Tt] = t_uhl;
      wzf[c][Tt] = t_wz;  wrf[c][Tt] = t_wr;  whf[c][Tt] = t_wh;
    }
  }

  const int ecol = lane & 31;                    // epilogue column (lanes<32 real)
  const float bzv = bz[jb + ecol];
  const float brv = br[jb + ecol];
  const float bhv = bh[jb + ecol];
  const int b_ep = GROWS * g + wv;               // epilogue batch row (wave==row)

  float hreg = 0.f;      // h(t) at (b_ep, jb+ecol), exact f32 (producer-side)
  float zvl  = 0.f;      // carried phase A -> phase B
  int budget = 4000000;  // bounded spins: fail loud, never hang

  for (int t = 0; t < GT; ++t) {
    const int par = t & 1;
    // ---- pre-wait: X fragments + mask (off the sync critical path) ----
    bf16x8 xa[2];
#pragma unroll
    for (int c = 0; c < 2; ++c) {
      const int k0 = kb + c * 32 + quad * 8;
      const float* xp = X + ((size_t)(GROWS * g + row8) * GT + t) * GDIN + k0;
      f32x4 x0 = *(const f32x4*)xp;
      f32x4 x1 = *(const f32x4*)(xp + 4);
      bf16x8 xf;
#pragma unroll
      for (int i = 0; i < 4; ++i) { xf[i] = f2bf(x0[i]); xf[i + 4] = f2bf(x1[i]); }
      xa[c] = xf;
    }
    const int mk = mask[(size_t)b_ep * GT + t];

    // ---- phase A: wait h(t), slab, frags, MFMAs (z, r, x-proj) ----
    if (t) wait16(hfl, (uint32_t)t, lane, wv, fast, budget);
    const uint32_t* hsrc = hb + ((size_t)par * NGRP + g) * (GROWS * GDOUT) + slab_off;
    u32x4 hd[4];
    if (fast) slab4_nt(hsrc, hd); else slab4_sc1(hsrc, hd);

    f32x4 az[2]  = {{0,0,0,0},{0,0,0,0}}, az2[2] = {{0,0,0,0},{0,0,0,0}};
    f32x4 ar[2]  = {{0,0,0,0},{0,0,0,0}}, ar2[2] = {{0,0,0,0},{0,0,0,0}};
    f32x4 ah[2]  = {{0,0,0,0},{0,0,0,0}};
#pragma unroll
    for (int c = 0; c < 2; ++c) {
      bf16x8 hhi, hlo;
      mk_frags(hd[2 * c], hd[2 * c + 1], hhi, hlo);
#pragma unroll
      for (int Tt = 0; Tt < 2; ++Tt) {   // independent chains for MFMA ILP
        az[Tt]  = __builtin_amdgcn_mfma_f32_16x16x32_bf16(hhi, uzh[c][Tt], az[Tt],  0, 0, 0);
        az2[Tt] = __builtin_amdgcn_mfma_f32_16x16x32_bf16(hlo, uzh[c][Tt], az2[Tt], 0, 0, 0);
        az[Tt]  = __builtin_amdgcn_mfma_f32_16x16x32_bf16(hhi, uzl[c][Tt], az[Tt],  0, 0, 0);
        az2[Tt] = __builtin_amdgcn_mfma_f32_16x16x32_bf16(xa[c], wzf[c][Tt], az2[Tt], 0, 0, 0);
        ar[Tt]  = __builtin_amdgcn_mfma_f32_16x16x32_bf16(hhi, urh[c][Tt], ar[Tt],  0, 0, 0);
        ar2[Tt] = __builtin_amdgcn_mfma_f32_16x16x32_bf16(hlo, urh[c][Tt], ar2[Tt], 0, 0, 0);
        ar[Tt]  = __builtin_amdgcn_mfma_f32_16x16x32_bf16(hhi, url[c][Tt], ar[Tt],  0, 0, 0);
        ar2[Tt] = __builtin_amdgcn_mfma_f32_16x16x32_bf16(xa[c], wrf[c][Tt], ar2[Tt], 0, 0, 0);
        ah[Tt]  = __builtin_amdgcn_mfma_f32_16x16x32_bf16(xa[c], whf[c][Tt], ah[Tt],  0, 0, 0);
      }
    }

    // ---- distributed reduce + per-wave rh release (1 barrier) ----
    if (quad < 2) {                      // quads 0-1 hold real rows 0-7
#pragma unroll
      for (int Tt = 0; Tt < 2; ++Tt)
#pragma unroll
        for (int rr = 0; rr < 4; ++rr) {
          scrA[par][wv][0][quad * 4 + rr][Tt * 16 + col16] = az[Tt][rr] + az2[Tt][rr];
          scrA[par][wv][1][quad * 4 + rr][Tt * 16 + col16] = ar[Tt][rr] + ar2[Tt][rr];
        }
    }
    __syncthreads();                     // joins all 8 waves' h-waits (all-16 coverage)

    float zsum = 0.f, rsum = 0.f;
#pragma unroll
    for (int w2 = 0; w2 < NWAVE; ++w2) {
      zsum += scrA[par][w2][0][wv][ecol];
      rsum += scrA[par][w2][1][wv][ecol];
    }
    zvl = 1.f / (1.f + __expf(-(zsum + bzv)));
    const float rvl = 1.f / (1.f + __expf(-(rsum + brv)));
    if (lane < 32) {
      uint32_t* dst = rhg + (size_t)wv * GDOUT + jb + lane;
      const uint32_t pv = pack_hl(rvl * hreg);
      if (fast) st_pl(dst, pv); else st_sc1(dst, pv);
    }
    vm_drain();                          // my 32 rh dwords committed (L2/MALL)
    if (lane == 0) {
      if (fast) st_pl(rfl_my, (uint32_t)(t + 1)); else st_sc1(rfl_my, (uint32_t)(t + 1));
    }

    // ---- phase B: wait rh(t), slab, 3 MFMA chains (Uh) ----
    wait16(rfl, (uint32_t)(t + 1), lane, wv, fast, budget);
    u32x4 rd[4];
    const uint32_t* rsrc = rhg + slab_off;
    if (fast) slab4_nt(rsrc, rd); else slab4_sc1(rsrc, rd);

    f32x4 b1[2] = {{0,0,0,0},{0,0,0,0}}, b2[2] = {{0,0,0,0},{0,0,0,0}};
    f32x4 b3[2] = {{0,0,0,0},{0,0,0,0}};
#pragma unroll
    for (int c = 0; c < 2; ++c) {
      bf16x8 th, tl;
      mk_frags(rd[2 * c], rd[2 * c + 1], th, tl);
#pragma unroll
      for (int Tt = 0; Tt < 2; ++Tt) {
        b1[Tt] = __builtin_amdgcn_mfma_f32_16x16x32_bf16(th, uhh[c][Tt], b1[Tt], 0, 0, 0);
        b2[Tt] = __builtin_amdgcn_mfma_f32_16x16x32_bf16(tl, uhh[c][Tt], b2[Tt], 0, 0, 0);
        b3[Tt] = __builtin_amdgcn_mfma_f32_16x16x32_bf16(th, uhl[c][Tt], b3[Tt], 0, 0, 0);
      }
    }

    if (quad < 2) {
#pragma unroll
      for (int Tt = 0; Tt < 2; ++Tt)
#pragma unroll
        for (int rr = 0; rr < 4; ++rr)
          scrB[par][wv][quad * 4 + rr][Tt * 16 + col16] =
              ah[Tt][rr] + b1[Tt][rr] + b2[Tt][rr] + b3[Tt][rr];
    }
    __syncthreads();                     // joins all 8 waves' rh-waits (all-16 coverage)

    float hsum = 0.f;
#pragma unroll
    for (int w2 = 0; w2 < NWAVE; ++w2) hsum += scrB[par][w2][wv][ecol];
    const float pre = hsum + bhv;
    const float e  = __expf(2.f * pre);              // tanh, saturation-safe
    const float hh = 1.f - 2.f / (e + 1.f);
    float hn = zvl * hreg + (1.f - zvl) * hh;
    hn = (mk > 0) ? hn : hreg;
    hreg = hn;

    if (lane < 32) {
      uint32_t* hdst = hb + ((size_t)((t + 1) & 1) * NGRP + g) * (GROWS * GDOUT)
                         + (size_t)wv * GDOUT + jb + lane;
      const uint32_t pv = pack_hl(hn);
      if (fast) st_pl(hdst, pv); else st_sc1(hdst, pv);
      if (t == GT - 1) out[(size_t)b_ep * GDOUT + jb + lane] = hn;
    }
    vm_drain();                          // my 32 h dwords committed
    if (lane == 0) {
      if (fast) st_pl(hfl_my, (uint32_t)(t + 1)); else st_sc1(hfl_my, (uint32_t)(t + 1));
    }
  }
}

extern "C" void kernel_launch(void* const* d_in, const int* in_sizes, int n_in,
                              void* d_out, int out_size, void* d_ws, size_t ws_size,
                              hipStream_t stream) {
  const float* X  = (const float*)d_in[0];
  const int* mask = (const int*)d_in[1];
  const float* Wz = (const float*)d_in[2];
  const float* Uz = (const float*)d_in[3];
  const float* bz = (const float*)d_in[4];
  const float* Wr = (const float*)d_in[5];
  const float* Ur = (const float*)d_in[6];
  const float* br = (const float*)d_in[7];
  const float* Wh = (const float*)d_in[8];
  const float* Uh = (const float*)d_in[9];
  const float* bh = (const float*)d_in[10];

  // zero h slot0 (packed 0x0 == 0.0f), rhb, flags, census/smoke
  hipMemsetAsync(d_ws, 0, (size_t)INIT_DW * 4, stream);

  hipLaunchKernelGGL(gru_fused, dim3(NWG), dim3(512), 0, stream,
                     X, mask, Wz, Uz, bz, Wr, Ur, br, Wh, Uh, bh,
                     (float*)d_out, (uint32_t*)d_ws);
}